// Round 21
// baseline (157.770 us; speedup 1.0000x reference)
//
#include <hip/hip_runtime.h>

#define HW    3136
#define CIN   64
#define MIDC  32
#define HEADS 8
#define DTOT  256
#define COUTC 64
#define WDIM  56
#define QT    64
#define L2E   1.4426950408889634f

typedef unsigned int uint_t;
typedef _Float16 f16;
typedef __attribute__((ext_vector_type(8))) _Float16 half8;
typedef __attribute__((ext_vector_type(2))) __fp16  fp16x2;
typedef __attribute__((ext_vector_type(4))) float f32x4;
typedef __attribute__((ext_vector_type(2))) float f32x2;

union HU { fp16x2 h; uint_t u; };
__device__ __forceinline__ uint_t pkh(float a, float b) {
    HU u; u.h = __builtin_amdgcn_cvt_pkrtz(a, b); return u.u;
}

// ---------------- Kernel 1: fused QKV conv + layout (fp32 in -> f16 ws) ------
// grid (99, 8): x<98 do the QKV tile; x==98 (8 blocks) convert Wo -> f16
// with permuted columns k' = h*32+m  (from original k = m*8+h).
__global__ __launch_bounds__(256) void qkv_fused_kernel(
    const float* __restrict__ x,
    const float* __restrict__ Wq, const float* __restrict__ bq,
    const float* __restrict__ Wk, const float* __restrict__ bk,
    const float* __restrict__ Wv, const float* __restrict__ bv,
    const float* __restrict__ Wo,
    f16* __restrict__ qh, f16* __restrict__ kh, f16* __restrict__ vh,
    f16* __restrict__ Wof)
{
    __shared__ float xs[64][36];
    __shared__ float Wlq[64][34];
    __shared__ float Wlk[64][34];
    __shared__ float Wlv[64][34];

    const int tid = threadIdx.x;
    const int h   = blockIdx.y;

    if (blockIdx.x == 98) {
        // Wo conversion: block y handles rows y*8 .. y*8+7
        int r  = blockIdx.y * 8 + (tid >> 5);     // out-channel row 0..63
        int kp = (tid & 31) * 8;                  // permuted col base
        half8 v;
        #pragma unroll
        for (int j = 0; j < 8; ++j) {
            int k2 = kp + j;                      // k' = h*32 + m
            int hh = k2 >> 5, mm = k2 & 31;
            v[j] = (f16)Wo[(size_t)r * DTOT + mm * HEADS + hh];
        }
        *(half8*)&Wof[(size_t)r * DTOT + kp] = v;
        return;
    }

    const int P0  = blockIdx.x * 32;

    {   int c = tid >> 2, g = tid & 3;
        const float* src = &x[(size_t)c * HW + P0 + g * 8];
        float4 v0 = *(const float4*)src;
        float4 v1 = *(const float4*)(src + 4);
        *(float4*)&xs[c][g * 8]     = v0;
        *(float4*)&xs[c][g * 8 + 4] = v1;
    }
    {   int m = tid >> 3, c8 = (tid & 7) * 8;
        size_t row = (size_t)(m * HEADS + h) * CIN + c8;
        float4 a0 = *(const float4*)&Wq[row], a1 = *(const float4*)&Wq[row + 4];
        float4 b0 = *(const float4*)&Wk[row], b1 = *(const float4*)&Wk[row + 4];
        float4 c0 = *(const float4*)&Wv[row], c1 = *(const float4*)&Wv[row + 4];
        #pragma unroll
        for (int i = 0; i < 4; ++i) {
            Wlq[c8 + i][m]     = ((const float*)&a0)[i];
            Wlq[c8 + 4 + i][m] = ((const float*)&a1)[i];
            Wlk[c8 + i][m]     = ((const float*)&b0)[i];
            Wlk[c8 + 4 + i][m] = ((const float*)&b1)[i];
            Wlv[c8 + i][m]     = ((const float*)&c0)[i];
            Wlv[c8 + 4 + i][m] = ((const float*)&c1)[i];
        }
    }
    __syncthreads();

    const int a  = tid & 15, pg = tid >> 4;
    const int m0 = a * 2,    p0 = pg * 2;
    const int d0 = m0 * HEADS + h, d1 = d0 + HEADS;

    float q00 = bq[d0], q01 = q00, q10 = bq[d1], q11 = q10;
    float k00 = bk[d0], k01 = k00, k10 = bk[d1], k11 = k10;
    float v00 = bv[d0], v01 = v00, v10 = bv[d1], v11 = v10;

    // 8B-aligned float2 LDS reads: p0/m0 even, row strides 144/136 B (8B-mult)
    #pragma unroll 8
    for (int c = 0; c < CIN; ++c) {
        f32x2 xv = *(const f32x2*)&xs[c][p0];
        f32x2 wq = *(const f32x2*)&Wlq[c][m0];
        f32x2 wk = *(const f32x2*)&Wlk[c][m0];
        f32x2 wv = *(const f32x2*)&Wlv[c][m0];
        q00 += wq.x * xv.x; q01 += wq.x * xv.y; q10 += wq.y * xv.x; q11 += wq.y * xv.y;
        k00 += wk.x * xv.x; k01 += wk.x * xv.y; k10 += wk.y * xv.x; k11 += wk.y * xv.y;
        v00 += wv.x * xv.x; v01 += wv.x * xv.y; v10 += wv.y * xv.x; v11 += wv.y * xv.y;
    }

    size_t qk0 = (size_t)h * HW * MIDC + (size_t)(P0 + p0) * MIDC + m0;
    *(uint_t*)&qh[qk0]        = pkh(q00, q10);
    *(uint_t*)&qh[qk0 + MIDC] = pkh(q01, q11);
    *(uint_t*)&kh[qk0]        = pkh(k00, k10);
    *(uint_t*)&kh[qk0 + MIDC] = pkh(k01, k11);
    size_t vb0 = (size_t)(h * MIDC + m0) * HW + P0 + p0;
    *(uint_t*)&vh[vb0]      = pkh(v00, v01);
    *(uint_t*)&vh[vb0 + HW] = pkh(v10, v11);
}

// ---------------- Kernel 2: MFMA flash attention, QT=64, K-split -------------
// grid (49, 8) = 392 blocks, 4 waves. R21: sc un-chunked back to sc[8] with
// launch_bounds(256,1) (cap 512). Rationale: R17's sc-chunking created a WAR
// hazard on the reused sc slab that FORBIDS hoisting chunk-1 QK MFMAs above
// chunk-0's exp (MfmaUtil 7.5% = matrix pipe idle during every exp phase).
// Occupancy is GRID-limited (1.53 blocks/CU, R18) so VGPR tier is free up to
// ~170. This is R16's schedule freedom + R17's liveness (qfrag from LDS)
// without R16's spill (VGPR-128 clamp under (256,2), 7.8MB scratch).
// Ledger: QT=16 78.5 | K-prefetch 63.0 | 8-wave 63.2 | reg-P 74.1 | bias-vec
// null | f16-bias 52.8 | QT=64+spill 56.5 | R17 chunked 49.7-51.2 (3 runs).
// Tripwire: WRITE_SIZE >> 1.57MB => RA spilled anyway => revert to R19.
// XCD head pin: lin = y*49+x, h = lin&7 (bijective, 392 = 8*49).
__global__ __launch_bounds__(256, 1) void attn_kernel(
    const f16* __restrict__ qh, const f16* __restrict__ kh,
    const f16* __restrict__ vh,
    const float* __restrict__ rowt, const float* __restrict__ colt,
    f16* __restrict__ obf)
{
    __shared__ __align__(16) char smem[51456];
    f16*   Qs  = (f16*)smem;                     // [64][32]   4096 B
    float* RbF = (float*)(smem + 4096);          // [64][57]  14592 B
    float* CbF = (float*)(smem + 18688);         // [64][60]  15360 B
    f16*   PlBase = (f16*)(smem + 34048);        // [4][16][136] 17408 B
    // merge overlay (valid after post-loop barrier):
    float* MOb = (float*)smem;                   // [4][64][36] 36864 B
    float* Ll  = (float*)(smem + 36864);         // [4][64]      1024 B

    const int tid   = threadIdx.x;
    const int wave  = tid >> 6, lane = tid & 63;
    const int lin   = blockIdx.y * 49 + blockIdx.x; // dispatch-linear id
    const int h     = lin & 7;                      // head per XCD
    const int qbase = (lin >> 3) * QT;
    const float c1  = 0.125f * L2E;

    const f16* Qh = qh + (size_t)h * HW * MIDC;
    const f16* Kh = kh + (size_t)h * HW * MIDC;
    const f16* Vh = vh + (size_t)h * MIDC * HW;

    {   // Qs load: 64 rows x 32 f16; 256 threads x 16B
        int r = tid >> 2, c = (tid & 3) * 8;
        *(uint4*)&Qs[r * MIDC + c] = *(const uint4*)&Qh[(size_t)(qbase + r) * MIDC + c];
    }
    __syncthreads();

    // bias tables: thread (q = tid>>2, sub = tid&3) covers kp = sub..<56 step 4
    {
        int q = tid >> 2, sub = tid & 3;
        int qg = qbase + q, qi = qg / WDIM, qj = qg % WDIM;
        half8 qr0 = *(const half8*)&Qs[q * MIDC + 0];
        half8 qr1 = *(const half8*)&Qs[q * MIDC + 8];
        half8 qr2 = *(const half8*)&Qs[q * MIDC + 16];
        half8 qr3 = *(const half8*)&Qs[q * MIDC + 24];
        for (int kp = sub; kp < WDIM; kp += 4) {
            const float4* rt4 = (const float4*)&rowt[(kp - qi + WDIM - 1) * 16];
            const float4* ct4 = (const float4*)&colt[(kp - qj + WDIM - 1) * 16];
            float4 r0 = rt4[0], r1 = rt4[1], r2 = rt4[2], r3 = rt4[3];
            float4 c0 = ct4[0], c1v = ct4[1], c2 = ct4[2], c3 = ct4[3];
            float s  = (float)qr0[0]*r0.x + (float)qr0[1]*r0.y + (float)qr0[2]*r0.z + (float)qr0[3]*r0.w
                     + (float)qr0[4]*r1.x + (float)qr0[5]*r1.y + (float)qr0[6]*r1.z + (float)qr0[7]*r1.w
                     + (float)qr1[0]*r2.x + (float)qr1[1]*r2.y + (float)qr1[2]*r2.z + (float)qr1[3]*r2.w
                     + (float)qr1[4]*r3.x + (float)qr1[5]*r3.y + (float)qr1[6]*r3.z + (float)qr1[7]*r3.w;
            float s2 = (float)qr2[0]*c0.x + (float)qr2[1]*c0.y + (float)qr2[2]*c0.z + (float)qr2[3]*c0.w
                     + (float)qr2[4]*c1v.x + (float)qr2[5]*c1v.y + (float)qr2[6]*c1v.z + (float)qr2[7]*c1v.w
                     + (float)qr3[0]*c2.x + (float)qr3[1]*c2.y + (float)qr3[2]*c2.z + (float)qr3[3]*c2.w
                     + (float)qr3[4]*c3.x + (float)qr3[5]*c3.y + (float)qr3[6]*c3.z + (float)qr3[7]*c3.w;
            RbF[q * 57 + kp] = s * c1;
            CbF[q * 60 + kp] = s2 * c1;
        }
    }
    __syncthreads();

    const int qL  = lane & 15;
    const int grp = lane >> 4;

    float lacc[4] = {0.f, 0.f, 0.f, 0.f};
    f32x4 o[4][2];
    #pragma unroll
    for (int i = 0; i < 4; ++i) { o[i][0] = (f32x4){0,0,0,0}; o[i][1] = (f32x4){0,0,0,0}; }

    int ki_s[8], kj_s[8];
    #pragma unroll
    for (int s = 0; s < 8; ++s) {
        int key0 = wave * 128 + s * 16 + grp * 4;
        ki_s[s] = key0 / WDIM;
        kj_s[s] = key0 % WDIM;                       // multiple of 4, <= 52
    }

    f16* Pw = PlBase + wave * (16 * 136);

    for (int j = 0; j < 6; ++j) {
        const int base = 512 * j + 128 * wave;

        half8 kfr[8];
        #pragma unroll
        for (int s = 0; s < 8; ++s)
            kfr[s] = *(const half8*)&Kh[(size_t)(base + s*16 + qL) * MIDC + grp*8];
        half8 vfr[2][4];
        #pragma unroll
        for (int ch = 0; ch < 2; ++ch)
            #pragma unroll
            for (int kf2 = 0; kf2 < 4; ++kf2)
                vfr[ch][kf2] = *(const half8*)
                    &Vh[(size_t)(ch*16 + qL) * HW + base + kf2*32 + grp*8];

        #pragma unroll
        for (int hf = 0; hf < 4; ++hf) {
            const int qrow = hf * 16 + qL;
            half8 qf = *(const half8*)&Qs[qrow * MIDC + grp * 8];   // from LDS
            f32x4 sc[8];                                 // unchunked: full ILP
            __builtin_amdgcn_s_setprio(1);
            #pragma unroll
            for (int s = 0; s < 8; ++s) {
                f32x4 z = {0.f,0.f,0.f,0.f};
                sc[s] = __builtin_amdgcn_mfma_f32_16x16x32_f16(kfr[s], qf, z, 0,0,0);
            }
            __builtin_amdgcn_s_setprio(0);
            #pragma unroll
            for (int s = 0; s < 8; ++s) {
                float rb = RbF[qrow * 57 + ki_s[s]];
                float4 cbv = *(const float4*)&CbF[qrow * 60 + kj_s[s]];
                float e0 = __builtin_amdgcn_exp2f(fmaf(sc[s][0], c1, rb + cbv.x));
                float e1 = __builtin_amdgcn_exp2f(fmaf(sc[s][1], c1, rb + cbv.y));
                float e2 = __builtin_amdgcn_exp2f(fmaf(sc[s][2], c1, rb + cbv.z));
                float e3 = __builtin_amdgcn_exp2f(fmaf(sc[s][3], c1, rb + cbv.w));
                lacc[hf] += (e0 + e1) + (e2 + e3);
                uint2 w2; w2.x = pkh(e0, e1); w2.y = pkh(e2, e3);
                *(uint2*)&Pw[qL * 136 + s * 16 + grp * 4] = w2;
            }
            __builtin_amdgcn_s_setprio(1);
            #pragma unroll
            for (int kf2 = 0; kf2 < 4; ++kf2) {
                half8 pf = *(const half8*)&Pw[qL * 136 + kf2 * 32 + grp * 8];
                o[hf][0] = __builtin_amdgcn_mfma_f32_16x16x32_f16(vfr[0][kf2], pf, o[hf][0], 0,0,0);
                o[hf][1] = __builtin_amdgcn_mfma_f32_16x16x32_f16(vfr[1][kf2], pf, o[hf][1], 0,0,0);
            }
            __builtin_amdgcn_s_setprio(0);
        }

        #pragma unroll
        for (int s = 0; s < 8; ++s) {                // advance keys by 512
            kj_s[s] += 8;
            if (kj_s[s] >= WDIM) { kj_s[s] -= WDIM; ki_s[s] += 10; }
            else                 { ki_s[s] += 9; }
        }
    }

    if (wave < 2) {        // tile 48 split: wave w handles keys 3072+32w..+31
        const int base = 3072 + wave * 32;
        half8 kfr[2];
        #pragma unroll
        for (int s = 0; s < 2; ++s)
            kfr[s] = *(const half8*)&Kh[(size_t)(base + s*16 + qL) * MIDC + grp*8];
        half8 vfr2[2];
        #pragma unroll
        for (int ch = 0; ch < 2; ++ch)
            vfr2[ch] = *(const half8*)
                &Vh[(size_t)(ch*16 + qL) * HW + base + grp*8];
        #pragma unroll
        for (int hf = 0; hf < 4; ++hf) {
            const int qrow = hf * 16 + qL;
            half8 qf = *(const half8*)&Qs[qrow * MIDC + grp * 8];
            f32x4 sc[2];
            #pragma unroll
            for (int s = 0; s < 2; ++s) {
                f32x4 z = {0.f,0.f,0.f,0.f};
                sc[s] = __builtin_amdgcn_mfma_f32_16x16x32_f16(kfr[s], qf, z, 0,0,0);
            }
            #pragma unroll
            for (int s = 0; s < 2; ++s) {
                int key0 = base + s * 16 + grp * 4;
                int ki = key0 / WDIM, kj = key0 % WDIM;
                float rb = RbF[qrow * 57 + ki];
                float4 cbv = *(const float4*)&CbF[qrow * 60 + kj];
                float e0 = __builtin_amdgcn_exp2f(fmaf(sc[s][0], c1, rb + cbv.x));
                float e1 = __builtin_amdgcn_exp2f(fmaf(sc[s][1], c1, rb + cbv.y));
                float e2 = __builtin_amdgcn_exp2f(fmaf(sc[s][2], c1, rb + cbv.z));
                float e3 = __builtin_amdgcn_exp2f(fmaf(sc[s][3], c1, rb + cbv.w));
                lacc[hf] += (e0 + e1) + (e2 + e3);
                uint2 w2; w2.x = pkh(e0, e1); w2.y = pkh(e2, e3);
                *(uint2*)&Pw[qL * 136 + s * 16 + grp * 4] = w2;
            }
            half8 pf = *(const half8*)&Pw[qL * 136 + grp * 8];
            o[hf][0] = __builtin_amdgcn_mfma_f32_16x16x32_f16(vfr2[0], pf, o[hf][0], 0,0,0);
            o[hf][1] = __builtin_amdgcn_mfma_f32_16x16x32_f16(vfr2[1], pf, o[hf][1], 0,0,0);
        }
    }

    #pragma unroll
    for (int hf = 0; hf < 4; ++hf) {
        lacc[hf] += __shfl_xor(lacc[hf], 16);
        lacc[hf] += __shfl_xor(lacc[hf], 32);
    }

    // merge 4 waves (each wave holds ALL 64 q-rows for its key subset)
    __syncthreads();
    #pragma unroll
    for (int hf = 0; hf < 4; ++hf) {
        int row = hf * 16 + qL;
        *(f32x4*)&MOb[(wave * 64 + row) * 36 + grp * 4]      = o[hf][0];
        *(f32x4*)&MOb[(wave * 64 + row) * 36 + 16 + grp * 4] = o[hf][1];
        if (grp == 0) Ll[wave * 64 + row] = lacc[hf];
    }
    __syncthreads();

    {
        int q = tid & 63, cseg = tid >> 6;       // cseg 0..3 -> 8 channels each
        float l = (Ll[q] + Ll[64+q]) + (Ll[128+q] + Ll[192+q]);
        float invl = 1.f / l;
        int qg = qbase + q;
        float av[8];
        #pragma unroll
        for (int i = 0; i < 8; ++i) {
            int ch = cseg * 8 + i;
            float acc = 0.f;
            #pragma unroll
            for (int w = 0; w < 4; ++w)
                acc += MOb[(w*64 + q) * 36 + ch];
            av[i] = acc * invl;
        }
        // f16 [pos][d'] layout, d' = h*32 + m  (matches permuted Wof columns)
        uint4 w4;
        w4.x = pkh(av[0], av[1]); w4.y = pkh(av[2], av[3]);
        w4.z = pkh(av[4], av[5]); w4.w = pkh(av[6], av[7]);
        *(uint4*)&obf[(size_t)qg * DTOT + h * MIDC + cseg * 8] = w4;
    }
}

// ---------------- Kernel 3: output 1x1 conv via MFMA -------------------------
// grid (196), 256 threads (4 waves). Wave w owns out-ch rows w*16..w*16+15;
// same math as the old single-wave mt-loop, re-partitioned for 4x TLP.
__global__ __launch_bounds__(256) void outproj_kernel(
    const f16* __restrict__ obf, const f16* __restrict__ Wof,
    const float* __restrict__ bo, float* __restrict__ out)
{
    const int tid  = threadIdx.x;
    const int mt   = tid >> 6;                   // wave index = out-ch tile
    const int lane = tid & 63;
    const int qL = lane & 15, grp = lane >> 4;
    const int p = blockIdx.x * 16 + qL;

    f32x4 acc = (f32x4){0,0,0,0};

    #pragma unroll
    for (int ks = 0; ks < 8; ++ks) {
        half8 bf = *(const half8*)&obf[(size_t)p * DTOT + ks * 32 + grp * 8];
        half8 af = *(const half8*)&Wof[(size_t)(mt * 16 + qL) * DTOT + ks * 32 + grp * 8];
        acc = __builtin_amdgcn_mfma_f32_16x16x32_f16(af, bf, acc, 0, 0, 0);
    }

    #pragma unroll
    for (int r = 0; r < 4; ++r) {
        int d = mt * 16 + grp * 4 + r;
        out[(size_t)d * HW + p] = acc[r] + bo[d];
    }
}

extern "C" void kernel_launch(void* const* d_in, const int* in_sizes, int n_in,
                              void* d_out, int out_size, void* d_ws, size_t ws_size,
                              hipStream_t stream)
{
    const float* x    = (const float*)d_in[0];
    const float* Wq   = (const float*)d_in[1];
    const float* bq   = (const float*)d_in[2];
    const float* Wk   = (const float*)d_in[3];
    const float* bk   = (const float*)d_in[4];
    const float* Wv   = (const float*)d_in[5];
    const float* bv   = (const float*)d_in[6];
    const float* Wo   = (const float*)d_in[7];
    const float* bo   = (const float*)d_in[8];
    const float* rowt = (const float*)d_in[9];
    const float* colt = (const float*)d_in[10];
    float* out = (float*)d_out;

    const size_t N = (size_t)DTOT * HW;
    f16* qh  = (f16*)d_ws;                       // [h][pos][32]
    f16* kh  = qh + N;
    f16* vh  = kh + N;                           // [h*32+m][pos]
    f16* obf = vh + N;                           // [pos][h*32+m] f16
    f16* Wof = obf + N;                          // [64][256] f16, permuted cols

    qkv_fused_kernel<<<dim3(99, HEADS), 256, 0, stream>>>(
        x, Wq, bq, Wk, bk, Wv, bv, Wo, qh, kh, vh, Wof);
    attn_kernel<<<dim3(HW / QT, HEADS), 256, 0, stream>>>(qh, kh, vh, rowt, colt, obf);
    outproj_kernel<<<dim3(HW / 16), 256, 0, stream>>>(obf, Wof, bo, out);
}

// Round 22
// 134.453 us; speedup vs baseline: 1.1734x; 1.1734x over previous
//
#include <hip/hip_runtime.h>

#define HW    3136
#define CIN   64
#define MIDC  32
#define HEADS 8
#define DTOT  256
#define COUTC 64
#define WDIM  56
#define QT    64
#define L2E   1.4426950408889634f

typedef unsigned int uint_t;
typedef _Float16 f16;
typedef __attribute__((ext_vector_type(8))) _Float16 half8;
typedef __attribute__((ext_vector_type(2))) __fp16  fp16x2;
typedef __attribute__((ext_vector_type(4))) float f32x4;
typedef __attribute__((ext_vector_type(2))) float f32x2;

union HU { fp16x2 h; uint_t u; };
__device__ __forceinline__ uint_t pkh(float a, float b) {
    HU u; u.h = __builtin_amdgcn_cvt_pkrtz(a, b); return u.u;
}

// ---------------- Kernel 1: fused QKV conv + layout (fp32 in -> f16 ws) ------
// grid (99, 8): x<98 do the QKV tile; x==98 (8 blocks) convert Wo -> f16
// with permuted columns k' = h*32+m  (from original k = m*8+h).
__global__ __launch_bounds__(256) void qkv_fused_kernel(
    const float* __restrict__ x,
    const float* __restrict__ Wq, const float* __restrict__ bq,
    const float* __restrict__ Wk, const float* __restrict__ bk,
    const float* __restrict__ Wv, const float* __restrict__ bv,
    const float* __restrict__ Wo,
    f16* __restrict__ qh, f16* __restrict__ kh, f16* __restrict__ vh,
    f16* __restrict__ Wof)
{
    __shared__ float xs[64][36];
    __shared__ float Wlq[64][34];
    __shared__ float Wlk[64][34];
    __shared__ float Wlv[64][34];

    const int tid = threadIdx.x;
    const int h   = blockIdx.y;

    if (blockIdx.x == 98) {
        // Wo conversion: block y handles rows y*8 .. y*8+7
        int r  = blockIdx.y * 8 + (tid >> 5);     // out-channel row 0..63
        int kp = (tid & 31) * 8;                  // permuted col base
        half8 v;
        #pragma unroll
        for (int j = 0; j < 8; ++j) {
            int k2 = kp + j;                      // k' = h*32 + m
            int hh = k2 >> 5, mm = k2 & 31;
            v[j] = (f16)Wo[(size_t)r * DTOT + mm * HEADS + hh];
        }
        *(half8*)&Wof[(size_t)r * DTOT + kp] = v;
        return;
    }

    const int P0  = blockIdx.x * 32;

    {   int c = tid >> 2, g = tid & 3;
        const float* src = &x[(size_t)c * HW + P0 + g * 8];
        float4 v0 = *(const float4*)src;
        float4 v1 = *(const float4*)(src + 4);
        *(float4*)&xs[c][g * 8]     = v0;
        *(float4*)&xs[c][g * 8 + 4] = v1;
    }
    {   int m = tid >> 3, c8 = (tid & 7) * 8;
        size_t row = (size_t)(m * HEADS + h) * CIN + c8;
        float4 a0 = *(const float4*)&Wq[row], a1 = *(const float4*)&Wq[row + 4];
        float4 b0 = *(const float4*)&Wk[row], b1 = *(const float4*)&Wk[row + 4];
        float4 c0 = *(const float4*)&Wv[row], c1 = *(const float4*)&Wv[row + 4];
        #pragma unroll
        for (int i = 0; i < 4; ++i) {
            Wlq[c8 + i][m]     = ((const float*)&a0)[i];
            Wlq[c8 + 4 + i][m] = ((const float*)&a1)[i];
            Wlk[c8 + i][m]     = ((const float*)&b0)[i];
            Wlk[c8 + 4 + i][m] = ((const float*)&b1)[i];
            Wlv[c8 + i][m]     = ((const float*)&c0)[i];
            Wlv[c8 + 4 + i][m] = ((const float*)&c1)[i];
        }
    }
    __syncthreads();

    const int a  = tid & 15, pg = tid >> 4;
    const int m0 = a * 2,    p0 = pg * 2;
    const int d0 = m0 * HEADS + h, d1 = d0 + HEADS;

    float q00 = bq[d0], q01 = q00, q10 = bq[d1], q11 = q10;
    float k00 = bk[d0], k01 = k00, k10 = bk[d1], k11 = k10;
    float v00 = bv[d0], v01 = v00, v10 = bv[d1], v11 = v10;

    // 8B-aligned float2 LDS reads: p0/m0 even, row strides 144/136 B (8B-mult)
    #pragma unroll 8
    for (int c = 0; c < CIN; ++c) {
        f32x2 xv = *(const f32x2*)&xs[c][p0];
        f32x2 wq = *(const f32x2*)&Wlq[c][m0];
        f32x2 wk = *(const f32x2*)&Wlk[c][m0];
        f32x2 wv = *(const f32x2*)&Wlv[c][m0];
        q00 += wq.x * xv.x; q01 += wq.x * xv.y; q10 += wq.y * xv.x; q11 += wq.y * xv.y;
        k00 += wk.x * xv.x; k01 += wk.x * xv.y; k10 += wk.y * xv.x; k11 += wk.y * xv.y;
        v00 += wv.x * xv.x; v01 += wv.x * xv.y; v10 += wv.y * xv.x; v11 += wv.y * xv.y;
    }

    size_t qk0 = (size_t)h * HW * MIDC + (size_t)(P0 + p0) * MIDC + m0;
    *(uint_t*)&qh[qk0]        = pkh(q00, q10);
    *(uint_t*)&qh[qk0 + MIDC] = pkh(q01, q11);
    *(uint_t*)&kh[qk0]        = pkh(k00, k10);
    *(uint_t*)&kh[qk0 + MIDC] = pkh(k01, k11);
    size_t vb0 = (size_t)(h * MIDC + m0) * HW + P0 + p0;
    *(uint_t*)&vh[vb0]      = pkh(v00, v01);
    *(uint_t*)&vh[vb0 + HW] = pkh(v10, v11);
}

// ---------------- Kernel 2: MFMA flash attention, QT=64, K-split -------------
// grid (49, 8) = 392 blocks, 4 waves. MEASURED-BEST (attn 49.7-51.2 us, total
// 132.8-134.0, 3 runs). Model: wall = T_block x 1.53 grid-limited generations;
// T_block ~ 5.6us fixed (K/V L2 stream) + 0.45*QT (latency chain).
// Failed-variant ledger (ALL measured, ALL reverted):
//   QT=16 78.5 | K-prefetch 63.0 (compiler sinks loads) | 8-wave 63.2 |
//   register-P 74.1 (V 16B->2x8B) | bias-vec null | f16-bias 52.8 (cvt in
//   exp path) | QT=64 unchunked@(256,2) 56.5 (VGPR-128 spill, 7.8MB scratch) |
//   sc[8]@(256,1) 75.2 (residency floor halved: Occ 13.6->8.0%, launch_bounds
//   min-waves is a scheduler provisioning hint, NOT just an RA cap).
// Liveness discipline (required at QT=64 under (256,2)): qfrag reloaded
// per-hf from LDS Qs; sc chunked 4-wide. VGPR 124, zero spill.
// XCD head pin: lin = y*49+x, h = lin&7 (bijective, 392 = 8*49).
__global__ __launch_bounds__(256, 2) void attn_kernel(
    const f16* __restrict__ qh, const f16* __restrict__ kh,
    const f16* __restrict__ vh,
    const float* __restrict__ rowt, const float* __restrict__ colt,
    f16* __restrict__ obf)
{
    __shared__ __align__(16) char smem[51456];
    f16*   Qs  = (f16*)smem;                     // [64][32]   4096 B
    float* RbF = (float*)(smem + 4096);          // [64][57]  14592 B
    float* CbF = (float*)(smem + 18688);         // [64][60]  15360 B
    f16*   PlBase = (f16*)(smem + 34048);        // [4][16][136] 17408 B
    // merge overlay (valid after post-loop barrier):
    float* MOb = (float*)smem;                   // [4][64][36] 36864 B
    float* Ll  = (float*)(smem + 36864);         // [4][64]      1024 B

    const int tid   = threadIdx.x;
    const int wave  = tid >> 6, lane = tid & 63;
    const int lin   = blockIdx.y * 49 + blockIdx.x; // dispatch-linear id
    const int h     = lin & 7;                      // head per XCD
    const int qbase = (lin >> 3) * QT;
    const float c1  = 0.125f * L2E;

    const f16* Qh = qh + (size_t)h * HW * MIDC;
    const f16* Kh = kh + (size_t)h * HW * MIDC;
    const f16* Vh = vh + (size_t)h * MIDC * HW;

    {   // Qs load: 64 rows x 32 f16; 256 threads x 16B
        int r = tid >> 2, c = (tid & 3) * 8;
        *(uint4*)&Qs[r * MIDC + c] = *(const uint4*)&Qh[(size_t)(qbase + r) * MIDC + c];
    }
    __syncthreads();

    // bias tables: thread (q = tid>>2, sub = tid&3) covers kp = sub..<56 step 4
    {
        int q = tid >> 2, sub = tid & 3;
        int qg = qbase + q, qi = qg / WDIM, qj = qg % WDIM;
        half8 qr0 = *(const half8*)&Qs[q * MIDC + 0];
        half8 qr1 = *(const half8*)&Qs[q * MIDC + 8];
        half8 qr2 = *(const half8*)&Qs[q * MIDC + 16];
        half8 qr3 = *(const half8*)&Qs[q * MIDC + 24];
        for (int kp = sub; kp < WDIM; kp += 4) {
            const float4* rt4 = (const float4*)&rowt[(kp - qi + WDIM - 1) * 16];
            const float4* ct4 = (const float4*)&colt[(kp - qj + WDIM - 1) * 16];
            float4 r0 = rt4[0], r1 = rt4[1], r2 = rt4[2], r3 = rt4[3];
            float4 c0 = ct4[0], c1v = ct4[1], c2 = ct4[2], c3 = ct4[3];
            float s  = (float)qr0[0]*r0.x + (float)qr0[1]*r0.y + (float)qr0[2]*r0.z + (float)qr0[3]*r0.w
                     + (float)qr0[4]*r1.x + (float)qr0[5]*r1.y + (float)qr0[6]*r1.z + (float)qr0[7]*r1.w
                     + (float)qr1[0]*r2.x + (float)qr1[1]*r2.y + (float)qr1[2]*r2.z + (float)qr1[3]*r2.w
                     + (float)qr1[4]*r3.x + (float)qr1[5]*r3.y + (float)qr1[6]*r3.z + (float)qr1[7]*r3.w;
            float s2 = (float)qr2[0]*c0.x + (float)qr2[1]*c0.y + (float)qr2[2]*c0.z + (float)qr2[3]*c0.w
                     + (float)qr2[4]*c1v.x + (float)qr2[5]*c1v.y + (float)qr2[6]*c1v.z + (float)qr2[7]*c1v.w
                     + (float)qr3[0]*c2.x + (float)qr3[1]*c2.y + (float)qr3[2]*c2.z + (float)qr3[3]*c2.w
                     + (float)qr3[4]*c3.x + (float)qr3[5]*c3.y + (float)qr3[6]*c3.z + (float)qr3[7]*c3.w;
            RbF[q * 57 + kp] = s * c1;
            CbF[q * 60 + kp] = s2 * c1;
        }
    }
    __syncthreads();

    const int qL  = lane & 15;
    const int grp = lane >> 4;

    float lacc[4] = {0.f, 0.f, 0.f, 0.f};
    f32x4 o[4][2];
    #pragma unroll
    for (int i = 0; i < 4; ++i) { o[i][0] = (f32x4){0,0,0,0}; o[i][1] = (f32x4){0,0,0,0}; }

    int ki_s[8], kj_s[8];
    #pragma unroll
    for (int s = 0; s < 8; ++s) {
        int key0 = wave * 128 + s * 16 + grp * 4;
        ki_s[s] = key0 / WDIM;
        kj_s[s] = key0 % WDIM;                       // multiple of 4, <= 52
    }

    f16* Pw = PlBase + wave * (16 * 136);

    for (int j = 0; j < 6; ++j) {
        const int base = 512 * j + 128 * wave;

        half8 kfr[8];
        #pragma unroll
        for (int s = 0; s < 8; ++s)
            kfr[s] = *(const half8*)&Kh[(size_t)(base + s*16 + qL) * MIDC + grp*8];
        half8 vfr[2][4];
        #pragma unroll
        for (int ch = 0; ch < 2; ++ch)
            #pragma unroll
            for (int kf2 = 0; kf2 < 4; ++kf2)
                vfr[ch][kf2] = *(const half8*)
                    &Vh[(size_t)(ch*16 + qL) * HW + base + kf2*32 + grp*8];

        #pragma unroll
        for (int hf = 0; hf < 4; ++hf) {
            const int qrow = hf * 16 + qL;
            half8 qf = *(const half8*)&Qs[qrow * MIDC + grp * 8];   // from LDS
            #pragma unroll
            for (int c4 = 0; c4 < 2; ++c4) {         // sc chunked: 4 live, not 8
                f32x4 sc[4];
                __builtin_amdgcn_s_setprio(1);
                #pragma unroll
                for (int s = 0; s < 4; ++s) {
                    f32x4 z = {0.f,0.f,0.f,0.f};
                    sc[s] = __builtin_amdgcn_mfma_f32_16x16x32_f16(kfr[c4*4+s], qf, z, 0,0,0);
                }
                __builtin_amdgcn_s_setprio(0);
                #pragma unroll
                for (int s = 0; s < 4; ++s) {
                    const int ss = c4 * 4 + s;
                    float rb = RbF[qrow * 57 + ki_s[ss]];
                    float4 cbv = *(const float4*)&CbF[qrow * 60 + kj_s[ss]];
                    float e0 = __builtin_amdgcn_exp2f(fmaf(sc[s][0], c1, rb + cbv.x));
                    float e1 = __builtin_amdgcn_exp2f(fmaf(sc[s][1], c1, rb + cbv.y));
                    float e2 = __builtin_amdgcn_exp2f(fmaf(sc[s][2], c1, rb + cbv.z));
                    float e3 = __builtin_amdgcn_exp2f(fmaf(sc[s][3], c1, rb + cbv.w));
                    lacc[hf] += (e0 + e1) + (e2 + e3);
                    uint2 w2; w2.x = pkh(e0, e1); w2.y = pkh(e2, e3);
                    *(uint2*)&Pw[qL * 136 + ss * 16 + grp * 4] = w2;
                }
            }
            __builtin_amdgcn_s_setprio(1);
            #pragma unroll
            for (int kf2 = 0; kf2 < 4; ++kf2) {
                half8 pf = *(const half8*)&Pw[qL * 136 + kf2 * 32 + grp * 8];
                o[hf][0] = __builtin_amdgcn_mfma_f32_16x16x32_f16(vfr[0][kf2], pf, o[hf][0], 0,0,0);
                o[hf][1] = __builtin_amdgcn_mfma_f32_16x16x32_f16(vfr[1][kf2], pf, o[hf][1], 0,0,0);
            }
            __builtin_amdgcn_s_setprio(0);
        }

        #pragma unroll
        for (int s = 0; s < 8; ++s) {                // advance keys by 512
            kj_s[s] += 8;
            if (kj_s[s] >= WDIM) { kj_s[s] -= WDIM; ki_s[s] += 10; }
            else                 { ki_s[s] += 9; }
        }
    }

    if (wave < 2) {        // tile 48 split: wave w handles keys 3072+32w..+31
        const int base = 3072 + wave * 32;
        half8 kfr[2];
        #pragma unroll
        for (int s = 0; s < 2; ++s)
            kfr[s] = *(const half8*)&Kh[(size_t)(base + s*16 + qL) * MIDC + grp*8];
        half8 vfr2[2];
        #pragma unroll
        for (int ch = 0; ch < 2; ++ch)
            vfr2[ch] = *(const half8*)
                &Vh[(size_t)(ch*16 + qL) * HW + base + grp*8];
        #pragma unroll
        for (int hf = 0; hf < 4; ++hf) {
            const int qrow = hf * 16 + qL;
            half8 qf = *(const half8*)&Qs[qrow * MIDC + grp * 8];
            f32x4 sc[2];
            #pragma unroll
            for (int s = 0; s < 2; ++s) {
                f32x4 z = {0.f,0.f,0.f,0.f};
                sc[s] = __builtin_amdgcn_mfma_f32_16x16x32_f16(kfr[s], qf, z, 0,0,0);
            }
            #pragma unroll
            for (int s = 0; s < 2; ++s) {
                int key0 = base + s * 16 + grp * 4;
                int ki = key0 / WDIM, kj = key0 % WDIM;
                float rb = RbF[qrow * 57 + ki];
                float4 cbv = *(const float4*)&CbF[qrow * 60 + kj];
                float e0 = __builtin_amdgcn_exp2f(fmaf(sc[s][0], c1, rb + cbv.x));
                float e1 = __builtin_amdgcn_exp2f(fmaf(sc[s][1], c1, rb + cbv.y));
                float e2 = __builtin_amdgcn_exp2f(fmaf(sc[s][2], c1, rb + cbv.z));
                float e3 = __builtin_amdgcn_exp2f(fmaf(sc[s][3], c1, rb + cbv.w));
                lacc[hf] += (e0 + e1) + (e2 + e3);
                uint2 w2; w2.x = pkh(e0, e1); w2.y = pkh(e2, e3);
                *(uint2*)&Pw[qL * 136 + s * 16 + grp * 4] = w2;
            }
            half8 pf = *(const half8*)&Pw[qL * 136 + grp * 8];
            o[hf][0] = __builtin_amdgcn_mfma_f32_16x16x32_f16(vfr2[0], pf, o[hf][0], 0,0,0);
            o[hf][1] = __builtin_amdgcn_mfma_f32_16x16x32_f16(vfr2[1], pf, o[hf][1], 0,0,0);
        }
    }

    #pragma unroll
    for (int hf = 0; hf < 4; ++hf) {
        lacc[hf] += __shfl_xor(lacc[hf], 16);
        lacc[hf] += __shfl_xor(lacc[hf], 32);
    }

    // merge 4 waves (each wave holds ALL 64 q-rows for its key subset)
    __syncthreads();
    #pragma unroll
    for (int hf = 0; hf < 4; ++hf) {
        int row = hf * 16 + qL;
        *(f32x4*)&MOb[(wave * 64 + row) * 36 + grp * 4]      = o[hf][0];
        *(f32x4*)&MOb[(wave * 64 + row) * 36 + 16 + grp * 4] = o[hf][1];
        if (grp == 0) Ll[wave * 64 + row] = lacc[hf];
    }
    __syncthreads();

    {
        int q = tid & 63, cseg = tid >> 6;       // cseg 0..3 -> 8 channels each
        float l = (Ll[q] + Ll[64+q]) + (Ll[128+q] + Ll[192+q]);
        float invl = 1.f / l;
        int qg = qbase + q;
        float av[8];
        #pragma unroll
        for (int i = 0; i < 8; ++i) {
            int ch = cseg * 8 + i;
            float acc = 0.f;
            #pragma unroll
            for (int w = 0; w < 4; ++w)
                acc += MOb[(w*64 + q) * 36 + ch];
            av[i] = acc * invl;
        }
        // f16 [pos][d'] layout, d' = h*32 + m  (matches permuted Wof columns)
        uint4 w4;
        w4.x = pkh(av[0], av[1]); w4.y = pkh(av[2], av[3]);
        w4.z = pkh(av[4], av[5]); w4.w = pkh(av[6], av[7]);
        *(uint4*)&obf[(size_t)qg * DTOT + h * MIDC + cseg * 8] = w4;
    }
}

// ---------------- Kernel 3: output 1x1 conv via MFMA -------------------------
// grid (196), 256 threads (4 waves). Wave w owns out-ch rows w*16..w*16+15;
// same math as the old single-wave mt-loop, re-partitioned for 4x TLP.
__global__ __launch_bounds__(256) void outproj_kernel(
    const f16* __restrict__ obf, const f16* __restrict__ Wof,
    const float* __restrict__ bo, float* __restrict__ out)
{
    const int tid  = threadIdx.x;
    const int mt   = tid >> 6;                   // wave index = out-ch tile
    const int lane = tid & 63;
    const int qL = lane & 15, grp = lane >> 4;
    const int p = blockIdx.x * 16 + qL;

    f32x4 acc = (f32x4){0,0,0,0};

    #pragma unroll
    for (int ks = 0; ks < 8; ++ks) {
        half8 bf = *(const half8*)&obf[(size_t)p * DTOT + ks * 32 + grp * 8];
        half8 af = *(const half8*)&Wof[(size_t)(mt * 16 + qL) * DTOT + ks * 32 + grp * 8];
        acc = __builtin_amdgcn_mfma_f32_16x16x32_f16(af, bf, acc, 0, 0, 0);
    }

    #pragma unroll
    for (int r = 0; r < 4; ++r) {
        int d = mt * 16 + grp * 4 + r;
        out[(size_t)d * HW + p] = acc[r] + bo[d];
    }
}

extern "C" void kernel_launch(void* const* d_in, const int* in_sizes, int n_in,
                              void* d_out, int out_size, void* d_ws, size_t ws_size,
                              hipStream_t stream)
{
    const float* x    = (const float*)d_in[0];
    const float* Wq   = (const float*)d_in[1];
    const float* bq   = (const float*)d_in[2];
    const float* Wk   = (const float*)d_in[3];
    const float* bk   = (const float*)d_in[4];
    const float* Wv   = (const float*)d_in[5];
    const float* bv   = (const float*)d_in[6];
    const float* Wo   = (const float*)d_in[7];
    const float* bo   = (const float*)d_in[8];
    const float* rowt = (const float*)d_in[9];
    const float* colt = (const float*)d_in[10];
    float* out = (float*)d_out;

    const size_t N = (size_t)DTOT * HW;
    f16* qh  = (f16*)d_ws;                       // [h][pos][32]
    f16* kh  = qh + N;
    f16* vh  = kh + N;                           // [h*32+m][pos]
    f16* obf = vh + N;                           // [pos][h*32+m] f16
    f16* Wof = obf + N;                          // [64][256] f16, permuted cols

    qkv_fused_kernel<<<dim3(99, HEADS), 256, 0, stream>>>(
        x, Wq, bq, Wk, bk, Wv, bv, Wo, qh, kh, vh, Wof);
    attn_kernel<<<dim3(HW / QT, HEADS), 256, 0, stream>>>(qh, kh, vh, rowt, colt, obf);
    outproj_kernel<<<dim3(HW / 16), 256, 0, stream>>>(obf, Wof, bo, out);
}

// Round 23
// 132.601 us; speedup vs baseline: 1.1898x; 1.0140x over previous
//
#include <hip/hip_runtime.h>

#define HW    3136
#define CIN   64
#define MIDC  32
#define HEADS 8
#define DTOT  256
#define COUTC 64
#define WDIM  56
#define QT    64
#define L2E   1.4426950408889634f

typedef unsigned int uint_t;
typedef _Float16 f16;
typedef __attribute__((ext_vector_type(8))) _Float16 half8;
typedef __attribute__((ext_vector_type(2))) __fp16  fp16x2;
typedef __attribute__((ext_vector_type(4))) float f32x4;
typedef __attribute__((ext_vector_type(2))) float f32x2;

union HU { fp16x2 h; uint_t u; };
__device__ __forceinline__ uint_t pkh(float a, float b) {
    HU u; u.h = __builtin_amdgcn_cvt_pkrtz(a, b); return u.u;
}

// ---------------- Kernel 1: fused QKV conv + layout (fp32 in -> f16 ws) ------
// grid (99, 8): x<98 do the QKV tile; x==98 (8 blocks) convert Wo -> f16
// with permuted columns k' = h*32+m  (from original k = m*8+h).
__global__ __launch_bounds__(256) void qkv_fused_kernel(
    const float* __restrict__ x,
    const float* __restrict__ Wq, const float* __restrict__ bq,
    const float* __restrict__ Wk, const float* __restrict__ bk,
    const float* __restrict__ Wv, const float* __restrict__ bv,
    const float* __restrict__ Wo,
    f16* __restrict__ qh, f16* __restrict__ kh, f16* __restrict__ vh,
    f16* __restrict__ Wof)
{
    __shared__ float xs[64][36];
    __shared__ float Wlq[64][34];
    __shared__ float Wlk[64][34];
    __shared__ float Wlv[64][34];

    const int tid = threadIdx.x;
    const int h   = blockIdx.y;

    if (blockIdx.x == 98) {
        // Wo conversion: block y handles rows y*8 .. y*8+7
        int r  = blockIdx.y * 8 + (tid >> 5);     // out-channel row 0..63
        int kp = (tid & 31) * 8;                  // permuted col base
        half8 v;
        #pragma unroll
        for (int j = 0; j < 8; ++j) {
            int k2 = kp + j;                      // k' = h*32 + m
            int hh = k2 >> 5, mm = k2 & 31;
            v[j] = (f16)Wo[(size_t)r * DTOT + mm * HEADS + hh];
        }
        *(half8*)&Wof[(size_t)r * DTOT + kp] = v;
        return;
    }

    const int P0  = blockIdx.x * 32;

    {   int c = tid >> 2, g = tid & 3;
        const float* src = &x[(size_t)c * HW + P0 + g * 8];
        float4 v0 = *(const float4*)src;
        float4 v1 = *(const float4*)(src + 4);
        *(float4*)&xs[c][g * 8]     = v0;
        *(float4*)&xs[c][g * 8 + 4] = v1;
    }
    {   int m = tid >> 3, c8 = (tid & 7) * 8;
        size_t row = (size_t)(m * HEADS + h) * CIN + c8;
        float4 a0 = *(const float4*)&Wq[row], a1 = *(const float4*)&Wq[row + 4];
        float4 b0 = *(const float4*)&Wk[row], b1 = *(const float4*)&Wk[row + 4];
        float4 c0 = *(const float4*)&Wv[row], c1 = *(const float4*)&Wv[row + 4];
        #pragma unroll
        for (int i = 0; i < 4; ++i) {
            Wlq[c8 + i][m]     = ((const float*)&a0)[i];
            Wlq[c8 + 4 + i][m] = ((const float*)&a1)[i];
            Wlk[c8 + i][m]     = ((const float*)&b0)[i];
            Wlk[c8 + 4 + i][m] = ((const float*)&b1)[i];
            Wlv[c8 + i][m]     = ((const float*)&c0)[i];
            Wlv[c8 + 4 + i][m] = ((const float*)&c1)[i];
        }
    }
    __syncthreads();

    const int a  = tid & 15, pg = tid >> 4;
    const int m0 = a * 2,    p0 = pg * 2;
    const int d0 = m0 * HEADS + h, d1 = d0 + HEADS;

    float q00 = bq[d0], q01 = q00, q10 = bq[d1], q11 = q10;
    float k00 = bk[d0], k01 = k00, k10 = bk[d1], k11 = k10;
    float v00 = bv[d0], v01 = v00, v10 = bv[d1], v11 = v10;

    // 8B-aligned float2 LDS reads: p0/m0 even, row strides 144/136 B (8B-mult)
    #pragma unroll 8
    for (int c = 0; c < CIN; ++c) {
        f32x2 xv = *(const f32x2*)&xs[c][p0];
        f32x2 wq = *(const f32x2*)&Wlq[c][m0];
        f32x2 wk = *(const f32x2*)&Wlk[c][m0];
        f32x2 wv = *(const f32x2*)&Wlv[c][m0];
        q00 += wq.x * xv.x; q01 += wq.x * xv.y; q10 += wq.y * xv.x; q11 += wq.y * xv.y;
        k00 += wk.x * xv.x; k01 += wk.x * xv.y; k10 += wk.y * xv.x; k11 += wk.y * xv.y;
        v00 += wv.x * xv.x; v01 += wv.x * xv.y; v10 += wv.y * xv.x; v11 += wv.y * xv.y;
    }

    size_t qk0 = (size_t)h * HW * MIDC + (size_t)(P0 + p0) * MIDC + m0;
    *(uint_t*)&qh[qk0]        = pkh(q00, q10);
    *(uint_t*)&qh[qk0 + MIDC] = pkh(q01, q11);
    *(uint_t*)&kh[qk0]        = pkh(k00, k10);
    *(uint_t*)&kh[qk0 + MIDC] = pkh(k01, k11);
    size_t vb0 = (size_t)(h * MIDC + m0) * HW + P0 + p0;
    *(uint_t*)&vh[vb0]      = pkh(v00, v01);
    *(uint_t*)&vh[vb0 + HW] = pkh(v10, v11);
}

// ---------------- Kernel 2: MFMA flash attention, QT=64, K-split -------------
// grid (49, 8) = 392 blocks, 4 waves. MEASURED-BEST (attn 49.6-51.2 us, total
// 132.8-134.5, 4 runs). Model: wall = T_block x 1.53 grid-limited generations;
// T_block ~ 5.6us fixed (K/V L2 stream) + 0.45*QT (latency chain).
// Failed-variant ledger (ALL measured, ALL reverted):
//   QT=16 78.5 | K-prefetch 63.0 (compiler sinks loads) | 8-wave 63.2 |
//   register-P 74.1 (V 16B->2x8B) | bias-vec null | f16-bias 52.8 (cvt in
//   exp path) | QT=64 unchunked@(256,2) 56.5 (VGPR-128 spill, 7.8MB scratch) |
//   sc[8]@(256,1) 75.2 (residency floor halved: Occ 13.6->8.0%, launch_bounds
//   min-waves is a scheduler provisioning hint, NOT just an RA cap).
// Liveness discipline (required at QT=64 under (256,2)): qfrag reloaded
// per-hf from LDS Qs; sc chunked 4-wide. VGPR 124, zero spill.
// XCD head pin: lin = y*49+x, h = lin&7 (bijective, 392 = 8*49).
__global__ __launch_bounds__(256, 2) void attn_kernel(
    const f16* __restrict__ qh, const f16* __restrict__ kh,
    const f16* __restrict__ vh,
    const float* __restrict__ rowt, const float* __restrict__ colt,
    f16* __restrict__ obf)
{
    __shared__ __align__(16) char smem[51456];
    f16*   Qs  = (f16*)smem;                     // [64][32]   4096 B
    float* RbF = (float*)(smem + 4096);          // [64][57]  14592 B
    float* CbF = (float*)(smem + 18688);         // [64][60]  15360 B
    f16*   PlBase = (f16*)(smem + 34048);        // [4][16][136] 17408 B
    // merge overlay (valid after post-loop barrier):
    float* MOb = (float*)smem;                   // [4][64][36] 36864 B
    float* Ll  = (float*)(smem + 36864);         // [4][64]      1024 B

    const int tid   = threadIdx.x;
    const int wave  = tid >> 6, lane = tid & 63;
    const int lin   = blockIdx.y * 49 + blockIdx.x; // dispatch-linear id
    const int h     = lin & 7;                      // head per XCD
    const int qbase = (lin >> 3) * QT;
    const float c1  = 0.125f * L2E;

    const f16* Qh = qh + (size_t)h * HW * MIDC;
    const f16* Kh = kh + (size_t)h * HW * MIDC;
    const f16* Vh = vh + (size_t)h * MIDC * HW;

    {   // Qs load: 64 rows x 32 f16; 256 threads x 16B
        int r = tid >> 2, c = (tid & 3) * 8;
        *(uint4*)&Qs[r * MIDC + c] = *(const uint4*)&Qh[(size_t)(qbase + r) * MIDC + c];
    }
    __syncthreads();

    // bias tables: thread (q = tid>>2, sub = tid&3) covers kp = sub..<56 step 4
    {
        int q = tid >> 2, sub = tid & 3;
        int qg = qbase + q, qi = qg / WDIM, qj = qg % WDIM;
        half8 qr0 = *(const half8*)&Qs[q * MIDC + 0];
        half8 qr1 = *(const half8*)&Qs[q * MIDC + 8];
        half8 qr2 = *(const half8*)&Qs[q * MIDC + 16];
        half8 qr3 = *(const half8*)&Qs[q * MIDC + 24];
        for (int kp = sub; kp < WDIM; kp += 4) {
            const float4* rt4 = (const float4*)&rowt[(kp - qi + WDIM - 1) * 16];
            const float4* ct4 = (const float4*)&colt[(kp - qj + WDIM - 1) * 16];
            float4 r0 = rt4[0], r1 = rt4[1], r2 = rt4[2], r3 = rt4[3];
            float4 c0 = ct4[0], c1v = ct4[1], c2 = ct4[2], c3 = ct4[3];
            float s  = (float)qr0[0]*r0.x + (float)qr0[1]*r0.y + (float)qr0[2]*r0.z + (float)qr0[3]*r0.w
                     + (float)qr0[4]*r1.x + (float)qr0[5]*r1.y + (float)qr0[6]*r1.z + (float)qr0[7]*r1.w
                     + (float)qr1[0]*r2.x + (float)qr1[1]*r2.y + (float)qr1[2]*r2.z + (float)qr1[3]*r2.w
                     + (float)qr1[4]*r3.x + (float)qr1[5]*r3.y + (float)qr1[6]*r3.z + (float)qr1[7]*r3.w;
            float s2 = (float)qr2[0]*c0.x + (float)qr2[1]*c0.y + (float)qr2[2]*c0.z + (float)qr2[3]*c0.w
                     + (float)qr2[4]*c1v.x + (float)qr2[5]*c1v.y + (float)qr2[6]*c1v.z + (float)qr2[7]*c1v.w
                     + (float)qr3[0]*c2.x + (float)qr3[1]*c2.y + (float)qr3[2]*c2.z + (float)qr3[3]*c2.w
                     + (float)qr3[4]*c3.x + (float)qr3[5]*c3.y + (float)qr3[6]*c3.z + (float)qr3[7]*c3.w;
            RbF[q * 57 + kp] = s * c1;
            CbF[q * 60 + kp] = s2 * c1;
        }
    }
    __syncthreads();

    const int qL  = lane & 15;
    const int grp = lane >> 4;

    float lacc[4] = {0.f, 0.f, 0.f, 0.f};
    f32x4 o[4][2];
    #pragma unroll
    for (int i = 0; i < 4; ++i) { o[i][0] = (f32x4){0,0,0,0}; o[i][1] = (f32x4){0,0,0,0}; }

    int ki_s[8], kj_s[8];
    #pragma unroll
    for (int s = 0; s < 8; ++s) {
        int key0 = wave * 128 + s * 16 + grp * 4;
        ki_s[s] = key0 / WDIM;
        kj_s[s] = key0 % WDIM;                       // multiple of 4, <= 52
    }

    f16* Pw = PlBase + wave * (16 * 136);

    for (int j = 0; j < 6; ++j) {
        const int base = 512 * j + 128 * wave;

        half8 kfr[8];
        #pragma unroll
        for (int s = 0; s < 8; ++s)
            kfr[s] = *(const half8*)&Kh[(size_t)(base + s*16 + qL) * MIDC + grp*8];
        half8 vfr[2][4];
        #pragma unroll
        for (int ch = 0; ch < 2; ++ch)
            #pragma unroll
            for (int kf2 = 0; kf2 < 4; ++kf2)
                vfr[ch][kf2] = *(const half8*)
                    &Vh[(size_t)(ch*16 + qL) * HW + base + kf2*32 + grp*8];

        #pragma unroll
        for (int hf = 0; hf < 4; ++hf) {
            const int qrow = hf * 16 + qL;
            half8 qf = *(const half8*)&Qs[qrow * MIDC + grp * 8];   // from LDS
            #pragma unroll
            for (int c4 = 0; c4 < 2; ++c4) {         // sc chunked: 4 live, not 8
                f32x4 sc[4];
                __builtin_amdgcn_s_setprio(1);
                #pragma unroll
                for (int s = 0; s < 4; ++s) {
                    f32x4 z = {0.f,0.f,0.f,0.f};
                    sc[s] = __builtin_amdgcn_mfma_f32_16x16x32_f16(kfr[c4*4+s], qf, z, 0,0,0);
                }
                __builtin_amdgcn_s_setprio(0);
                #pragma unroll
                for (int s = 0; s < 4; ++s) {
                    const int ss = c4 * 4 + s;
                    float rb = RbF[qrow * 57 + ki_s[ss]];
                    float4 cbv = *(const float4*)&CbF[qrow * 60 + kj_s[ss]];
                    float e0 = __builtin_amdgcn_exp2f(fmaf(sc[s][0], c1, rb + cbv.x));
                    float e1 = __builtin_amdgcn_exp2f(fmaf(sc[s][1], c1, rb + cbv.y));
                    float e2 = __builtin_amdgcn_exp2f(fmaf(sc[s][2], c1, rb + cbv.z));
                    float e3 = __builtin_amdgcn_exp2f(fmaf(sc[s][3], c1, rb + cbv.w));
                    lacc[hf] += (e0 + e1) + (e2 + e3);
                    uint2 w2; w2.x = pkh(e0, e1); w2.y = pkh(e2, e3);
                    *(uint2*)&Pw[qL * 136 + ss * 16 + grp * 4] = w2;
                }
            }
            __builtin_amdgcn_s_setprio(1);
            #pragma unroll
            for (int kf2 = 0; kf2 < 4; ++kf2) {
                half8 pf = *(const half8*)&Pw[qL * 136 + kf2 * 32 + grp * 8];
                o[hf][0] = __builtin_amdgcn_mfma_f32_16x16x32_f16(vfr[0][kf2], pf, o[hf][0], 0,0,0);
                o[hf][1] = __builtin_amdgcn_mfma_f32_16x16x32_f16(vfr[1][kf2], pf, o[hf][1], 0,0,0);
            }
            __builtin_amdgcn_s_setprio(0);
        }

        #pragma unroll
        for (int s = 0; s < 8; ++s) {                // advance keys by 512
            kj_s[s] += 8;
            if (kj_s[s] >= WDIM) { kj_s[s] -= WDIM; ki_s[s] += 10; }
            else                 { ki_s[s] += 9; }
        }
    }

    if (wave < 2) {        // tile 48 split: wave w handles keys 3072+32w..+31
        const int base = 3072 + wave * 32;
        half8 kfr[2];
        #pragma unroll
        for (int s = 0; s < 2; ++s)
            kfr[s] = *(const half8*)&Kh[(size_t)(base + s*16 + qL) * MIDC + grp*8];
        half8 vfr2[2];
        #pragma unroll
        for (int ch = 0; ch < 2; ++ch)
            vfr2[ch] = *(const half8*)
                &Vh[(size_t)(ch*16 + qL) * HW + base + grp*8];
        #pragma unroll
        for (int hf = 0; hf < 4; ++hf) {
            const int qrow = hf * 16 + qL;
            half8 qf = *(const half8*)&Qs[qrow * MIDC + grp * 8];
            f32x4 sc[2];
            #pragma unroll
            for (int s = 0; s < 2; ++s) {
                f32x4 z = {0.f,0.f,0.f,0.f};
                sc[s] = __builtin_amdgcn_mfma_f32_16x16x32_f16(kfr[s], qf, z, 0,0,0);
            }
            #pragma unroll
            for (int s = 0; s < 2; ++s) {
                int key0 = base + s * 16 + grp * 4;
                int ki = key0 / WDIM, kj = key0 % WDIM;
                float rb = RbF[qrow * 57 + ki];
                float4 cbv = *(const float4*)&CbF[qrow * 60 + kj];
                float e0 = __builtin_amdgcn_exp2f(fmaf(sc[s][0], c1, rb + cbv.x));
                float e1 = __builtin_amdgcn_exp2f(fmaf(sc[s][1], c1, rb + cbv.y));
                float e2 = __builtin_amdgcn_exp2f(fmaf(sc[s][2], c1, rb + cbv.z));
                float e3 = __builtin_amdgcn_exp2f(fmaf(sc[s][3], c1, rb + cbv.w));
                lacc[hf] += (e0 + e1) + (e2 + e3);
                uint2 w2; w2.x = pkh(e0, e1); w2.y = pkh(e2, e3);
                *(uint2*)&Pw[qL * 136 + s * 16 + grp * 4] = w2;
            }
            half8 pf = *(const half8*)&Pw[qL * 136 + grp * 8];
            o[hf][0] = __builtin_amdgcn_mfma_f32_16x16x32_f16(vfr2[0], pf, o[hf][0], 0,0,0);
            o[hf][1] = __builtin_amdgcn_mfma_f32_16x16x32_f16(vfr2[1], pf, o[hf][1], 0,0,0);
        }
    }

    #pragma unroll
    for (int hf = 0; hf < 4; ++hf) {
        lacc[hf] += __shfl_xor(lacc[hf], 16);
        lacc[hf] += __shfl_xor(lacc[hf], 32);
    }

    // merge 4 waves (each wave holds ALL 64 q-rows for its key subset)
    __syncthreads();
    #pragma unroll
    for (int hf = 0; hf < 4; ++hf) {
        int row = hf * 16 + qL;
        *(f32x4*)&MOb[(wave * 64 + row) * 36 + grp * 4]      = o[hf][0];
        *(f32x4*)&MOb[(wave * 64 + row) * 36 + 16 + grp * 4] = o[hf][1];
        if (grp == 0) Ll[wave * 64 + row] = lacc[hf];
    }
    __syncthreads();

    {
        int q = tid & 63, cseg = tid >> 6;       // cseg 0..3 -> 8 channels each
        float l = (Ll[q] + Ll[64+q]) + (Ll[128+q] + Ll[192+q]);
        float invl = 1.f / l;
        int qg = qbase + q;
        float av[8];
        #pragma unroll
        for (int i = 0; i < 8; ++i) {
            int ch = cseg * 8 + i;
            float acc = 0.f;
            #pragma unroll
            for (int w = 0; w < 4; ++w)
                acc += MOb[(w*64 + q) * 36 + ch];
            av[i] = acc * invl;
        }
        // f16 [pos][d'] layout, d' = h*32 + m  (matches permuted Wof columns)
        uint4 w4;
        w4.x = pkh(av[0], av[1]); w4.y = pkh(av[2], av[3]);
        w4.z = pkh(av[4], av[5]); w4.w = pkh(av[6], av[7]);
        *(uint4*)&obf[(size_t)qg * DTOT + h * MIDC + cseg * 8] = w4;
    }
}

// ---------------- Kernel 3: output 1x1 conv via MFMA -------------------------
// grid (196), 256 threads (4 waves). Wave w owns out-ch rows w*16..w*16+15;
// same math as the old single-wave mt-loop, re-partitioned for 4x TLP.
__global__ __launch_bounds__(256) void outproj_kernel(
    const f16* __restrict__ obf, const f16* __restrict__ Wof,
    const float* __restrict__ bo, float* __restrict__ out)
{
    const int tid  = threadIdx.x;
    const int mt   = tid >> 6;                   // wave index = out-ch tile
    const int lane = tid & 63;
    const int qL = lane & 15, grp = lane >> 4;
    const int p = blockIdx.x * 16 + qL;

    f32x4 acc = (f32x4){0,0,0,0};

    #pragma unroll
    for (int ks = 0; ks < 8; ++ks) {
        half8 bf = *(const half8*)&obf[(size_t)p * DTOT + ks * 32 + grp * 8];
        half8 af = *(const half8*)&Wof[(size_t)(mt * 16 + qL) * DTOT + ks * 32 + grp * 8];
        acc = __builtin_amdgcn_mfma_f32_16x16x32_f16(af, bf, acc, 0, 0, 0);
    }

    #pragma unroll
    for (int r = 0; r < 4; ++r) {
        int d = mt * 16 + grp * 4 + r;
        out[(size_t)d * HW + p] = acc[r] + bo[d];
    }
}

extern "C" void kernel_launch(void* const* d_in, const int* in_sizes, int n_in,
                              void* d_out, int out_size, void* d_ws, size_t ws_size,
                              hipStream_t stream)
{
    const float* x    = (const float*)d_in[0];
    const float* Wq   = (const float*)d_in[1];
    const float* bq   = (const float*)d_in[2];
    const float* Wk   = (const float*)d_in[3];
    const float* bk   = (const float*)d_in[4];
    const float* Wv   = (const float*)d_in[5];
    const float* bv   = (const float*)d_in[6];
    const float* Wo   = (const float*)d_in[7];
    const float* bo   = (const float*)d_in[8];
    const float* rowt = (const float*)d_in[9];
    const float* colt = (const float*)d_in[10];
    float* out = (float*)d_out;

    const size_t N = (size_t)DTOT * HW;
    f16* qh  = (f16*)d_ws;                       // [h][pos][32]
    f16* kh  = qh + N;
    f16* vh  = kh + N;                           // [h*32+m][pos]
    f16* obf = vh + N;                           // [pos][h*32+m] f16
    f16* Wof = obf + N;                          // [64][256] f16, permuted cols

    qkv_fused_kernel<<<dim3(99, HEADS), 256, 0, stream>>>(
        x, Wq, bq, Wk, bk, Wv, bv, Wo, qh, kh, vh, Wof);
    attn_kernel<<<dim3(HW / QT, HEADS), 256, 0, stream>>>(qh, kh, vh, rowt, colt, obf);
    outproj_kernel<<<dim3(HW / 16), 256, 0, stream>>>(obf, Wof, bo, out);
}